// Round 14
// baseline (256.620 us; speedup 1.0000x reference)
//
#include <hip/hip_runtime.h>
#include <hip/hip_bf16.h>

#define LSEQ   16384
#define BATCH  32
#define NBS    64              // B*2 sequences
#define NW     8000
#define CHUNK  448             // output rows per block
#define NCHK   37              // ceil(16384/448)
#define ROWS   536             // LDS plane rows: seq [base-32, base+504)
#define RSW    12              // dense row stride in ushorts (10 data + 2 zero-pad)
#define NT9    9               // k-steps: ceil(22*12/32)=9 (K padded 264->288)

typedef short v8s __attribute__((ext_vector_type(8)));   // 8 bf16 = 4 VGPR
typedef short v4s __attribute__((ext_vector_type(4)));   // 4 bf16 = 2 VGPR (8B)
typedef float v4f __attribute__((ext_vector_type(4)));   // MFMA acc
typedef _Float16 hf2 __attribute__((ext_vector_type(2)));  // packed f16 pair

__device__ __forceinline__ unsigned short f2bf(float f) {   // RTNE f32->bf16
  unsigned u = __float_as_uint(f);
  unsigned r = u + 0x7FFFu + ((u >> 16) & 1u);
  return (unsigned short)(r >> 16);
}
__device__ __forceinline__ unsigned short cvt_bf16(float v) {  // HW cvt
  __hip_bfloat16 hb = __float2bfloat16(v);
  unsigned short us;
  __builtin_memcpy(&us, &hb, 2);
  return us;
}

// ---------------------------------------------------------------------------
// Prep: blocks 0..31 build bf16 emb table [NW+1][16] (elems 10..15 = 0);
// blocks 32..38 build MFMA B-fragments for the DENSE im2col (k = kh*12 + wi):
//   B[k][n] = W[kh][wi-n+10] for wi<10, n<10, 0<=wi-n+10<22, kh<22; else 0.
// B-operand layout (mfma_f32_16x16x32_bf16): lane l holds
//   B[k = 32t + 8*(l>>4) + j][col = l&15], j = 0..7.
// ---------------------------------------------------------------------------
__global__ __launch_bounds__(256) void prep_kernel(
    const float* __restrict__ emb, const float* __restrict__ w1,
    const float* __restrict__ w2, const float* __restrict__ w3,
    unsigned short* __restrict__ emb16, unsigned short* __restrict__ bh) {
  int bid = blockIdx.x;
  if (bid < 32) {
    int r = bid * 256 + threadIdx.x;
    if (r > NW) return;
    const float2* er = reinterpret_cast<const float2*>(emb + r * 10);
    float v[10];
#pragma unroll
    for (int k = 0; k < 5; ++k) { float2 t2 = er[k]; v[2 * k] = t2.x; v[2 * k + 1] = t2.y; }
    v8s lo8 = (v8s)0, hi8 = (v8s)0;
#pragma unroll
    for (int j = 0; j < 8; ++j) lo8[j] = (short)f2bf(v[j]);
    hi8[0] = (short)f2bf(v[8]);
    hi8[1] = (short)f2bf(v[9]);
    v8s* dst = reinterpret_cast<v8s*>(emb16 + r * 16);
    dst[0] = lo8;
    dst[1] = hi8;
  } else {
    int idx = (bid - 32) * 256 + threadIdx.x;   // (stage*9 + t)*64 + lane
    if (idx >= 3 * NT9 * 64) return;
    int lane = idx & 63, rest = idx >> 6;
    int t = rest % NT9, stage = rest / NT9;
    const float* W = (stage == 0) ? w1 : (stage == 1) ? w2 : w3;
    int col = lane & 15;
#pragma unroll
    for (int j = 0; j < 8; ++j) {
      int k = 32 * t + 8 * (lane >> 4) + j;
      int kh = k / 12, wi = k - 12 * kh;
      int kw = wi - col + 10;
      float v = (wi < 10 && col < 10 && kh < 22 && kw >= 0 && kw < 22)
                    ? W[kh * 22 + kw] : 0.0f;
      bh[idx * 8 + j] = f2bf(v);
    }
  }
}

// ---------------------------------------------------------------------------
// Packed-pair (two channels per u32, f16x2) bitonic primitives (r12-verified).
// ---------------------------------------------------------------------------
__device__ __forceinline__ unsigned h2max_u(unsigned a, unsigned b) {
  hf2 r = __builtin_elementwise_max(__builtin_bit_cast(hf2, a),
                                    __builtin_bit_cast(hf2, b));
  return __builtin_bit_cast(unsigned, r);
}
__device__ __forceinline__ unsigned h2min_u(unsigned a, unsigned b) {
  hf2 r = __builtin_elementwise_min(__builtin_bit_cast(hf2, a),
                                    __builtin_bit_cast(hf2, b));
  return __builtin_bit_cast(unsigned, r);
}
__device__ __forceinline__ unsigned bsort64_h2(unsigned v, int lane) {
#pragma unroll
  for (int k = 2; k <= 64; k <<= 1) {
#pragma unroll
    for (int j = k >> 1; j > 0; j >>= 1) {
      unsigned o = __shfl_xor(v, j, 64);
      bool keepmax = (((lane & k) == 0) == ((lane & j) == 0));
      unsigned mx = h2max_u(v, o), mn = h2min_u(v, o);
      v = keepmax ? mx : mn;
    }
  }
  return v;
}
__device__ __forceinline__ unsigned bmerge64_h2(unsigned a, unsigned b, int lane) {
  unsigned rb = __shfl(b, 63 - lane, 64);
  unsigned m = h2max_u(a, rb);
#pragma unroll
  for (int j = 32; j > 0; j >>= 1) {
    unsigned o = __shfl_xor(m, j, 64);
    unsigned mx = h2max_u(m, o), mn = h2min_u(m, o);
    m = ((lane & j) == 0) ? mx : mn;
  }
  return m;
}

// ---------------------------------------------------------------------------
// Fused 3-layer conv via bf16 MFMA on a DENSE (stride-12) plane.
// Contiguity identity: A[out_r][k=kh*12+wi] = plane[(out_r-10)*12 + k], so a
// lane's 8 consecutive k are 8 consecutive ushorts -> two 8B ds_read_b64
// (8B-aligned: all offsets are multiples of 4 ushorts). 9 k-steps (was 11),
// 810 MFMAs/block (was 990). Row stride 6 dwords -> 16 distinct start banks
// per 16 lanes (was 8 with stride-12-dwords -> kills the structural 2-way).
// ---------------------------------------------------------------------------
__global__ __launch_bounds__(512, 6) void conv_fused_kernel(
    const int* __restrict__ inputs, const unsigned short* __restrict__ emb16,
    const float* __restrict__ b1, const float* __restrict__ b2,
    const float* __restrict__ b3,
    const unsigned short* __restrict__ bh,
    unsigned* __restrict__ candp /* [NBS*5][NCHK][50] packed */) {
  __shared__ unsigned short plane[ROWS * RSW];   // 12.9 KB

  int blk = blockIdx.x;
  int bs = blk / NCHK;
  int chunk = blk - bs * NCHK;
  int base = chunk * CHUNK;
  int tid = threadIdx.x;
  int lane = tid & 63, wave = tid >> 6;

  // ---- gather: copy bf16 emb rows (12 of 16 table elems; 10,11 are zero) ----
  const int* tokp = inputs + bs * LSEQ;
  for (int i = tid; i < ROWS; i += 512) {
    int seq = base - 32 + i;
    v4s a0 = (v4s)0, a1 = (v4s)0, a2 = (v4s)0;
    if ((unsigned)seq < (unsigned)LSEQ) {
      int tok = tokp[seq];
      const v4s* er = reinterpret_cast<const v4s*>(emb16 + tok * 16);
      a0 = er[0]; a1 = er[1]; a2 = er[2];
    }
    *reinterpret_cast<v4s*>(&plane[i * RSW + 0]) = a0;
    *reinterpret_cast<v4s*>(&plane[i * RSW + 4]) = a1;
    *reinterpret_cast<v4s*>(&plane[i * RSW + 8]) = a2;
  }
  __syncthreads();

  // lane-constant A offset: ((l&15) - 10 + 32 rows)*12 + 8*(l>>4)
  const int laneA = ((lane & 15) + 22) * RSW + 8 * (lane >> 4);
  const int col = lane & 15;
  const int rbase = ((lane >> 4) & 3) * 4;

#pragma unroll 1
  for (int stage = 0; stage < 3; ++stage) {
    const int lo = (stage == 0) ? -20 : (stage == 1) ? -10 : 0;
    const int ntiles = (stage == 0) ? 32 : (stage == 1) ? 30 : 28;
    const float bias = (stage == 0) ? b1[0] : (stage == 1) ? b2[0] : b3[0];
    const int nt = (ntiles - wave + 7) >> 3;     // tiles wave+8m, m<nt

    v4f acc[4];
#pragma unroll
    for (int m = 0; m < 4; ++m)
#pragma unroll
      for (int j = 0; j < 4; ++j) acc[m][j] = 0.0f;

    const v8s* bhf = reinterpret_cast<const v8s*>(bh) + (stage * NT9) * 64 + lane;
    v8s bhc = bhf[0];

#pragma unroll 1
    for (int t = 0; t < NT9; ++t) {
      v8s bhn = bhc;
      if (t < NT9 - 1) bhn = bhf[(t + 1) * 64];
      const int toff = laneA + t * 32;
#pragma unroll
      for (int m = 0; m < 4; ++m) {
        if (m < nt) {
          int r0 = lo + (wave + 8 * m) * 16;
          int off = toff + r0 * RSW;
          v4s alo = *reinterpret_cast<const v4s*>(&plane[off]);
          v4s ahi = *reinterpret_cast<const v4s*>(&plane[off + 4]);
          v8s a;
#pragma unroll
          for (int q = 0; q < 4; ++q) { a[q] = alo[q]; a[4 + q] = ahi[q]; }
          acc[m] = __builtin_amdgcn_mfma_f32_16x16x32_bf16(a, bhc, acc[m], 0, 0, 0);
        }
      }
      bhc = bhn;
    }
    __syncthreads();   // all reads complete before in-place writes

#pragma unroll
    for (int m = 0; m < 4; ++m) {
      if (m < nt) {
        int r0 = lo + (wave + 8 * m) * 16;
#pragma unroll
        for (int j = 0; j < 4; ++j) {
          int rloc = r0 + rbase + j;
          int seq = base + rloc;
          unsigned short us = cvt_bf16(fmaxf(acc[m][j] + bias, 0.0f));
          bool ok = (col < 10) && ((unsigned)seq < (unsigned)LSEQ);
          if (col < 12)
            plane[(rloc + 32) * RSW + col] = ok ? us : (unsigned short)0;
        }
      }
    }
    __syncthreads();
  }

  // ---- per-chunk exact top-50, one packed channel-pair stream per wave ----
  if (wave < 5) {
    int p = wave;                              // cols 2p, 2p+1
    unsigned x[7];
#pragma unroll
    for (int s = 0; s < 7; ++s) {
      unsigned w = *reinterpret_cast<const unsigned*>(
          &plane[(32 + s * 64 + lane) * RSW + 2 * p]);
      float flo = __uint_as_float(w << 16);          // bf16 lo -> f32 (exact)
      float fhi = __uint_as_float(w & 0xFFFF0000u);  // bf16 hi -> f32 (exact)
      hf2 h;
      h[0] = (_Float16)flo;                          // f32 -> f16 (exact here)
      h[1] = (_Float16)fhi;
      x[s] = __builtin_bit_cast(unsigned, h);
    }
#pragma unroll
    for (int s = 0; s < 7; ++s) x[s] = bsort64_h2(x[s], lane);
    unsigned y0 = bmerge64_h2(x[0], x[1], lane);
    unsigned y1 = bmerge64_h2(x[2], x[3], lane);
    unsigned y2 = bmerge64_h2(x[4], x[5], lane);
    unsigned z0 = bmerge64_h2(y0, y1, lane);
    unsigned z1 = bmerge64_h2(y2, x[6], lane);
    unsigned t  = bmerge64_h2(z0, z1, lane);
    if (lane < 50)
      candp[((bs * 5 + p) * NCHK + chunk) * 50 + lane] = t;
  }
}

// ---------------------------------------------------------------------------
// Merge: per (bs, channel-pair), top-50 of 37*50=1850 packed candidates.
// ---------------------------------------------------------------------------
__global__ __launch_bounds__(256) void merge_topk_kernel(
    const unsigned* __restrict__ candp, float* __restrict__ fbuf) {
  __shared__ unsigned ml[2048];
  int blk = blockIdx.x;            // bs*5 + p
  int tid = threadIdx.x;
  const unsigned* src = candp + blk * (NCHK * 50);
  for (int i = tid; i < 2048; i += 256) ml[i] = (i < NCHK * 50) ? src[i] : 0u;
  for (int k = 2; k <= 2048; k <<= 1) {
    for (int j = k >> 1; j > 0; j >>= 1) {
      __syncthreads();
      for (int e = tid; e < 1024; e += 256) {
        int lo = ((e & ~(j - 1)) << 1) | (e & (j - 1));
        int hi = lo | j;
        unsigned a = ml[lo], b = ml[hi];
        bool desc = ((lo & k) == 0);
        unsigned mx = h2max_u(a, b), mn = h2min_u(a, b);
        ml[lo] = desc ? mx : mn;
        ml[hi] = desc ? mn : mx;
      }
    }
  }
  __syncthreads();
  if (tid < 50) {
    int bs = blk / 5, p = blk - bs * 5;
    hf2 h = __builtin_bit_cast(hf2, ml[tid]);
    fbuf[bs * 500 + tid * 10 + 2 * p + 0] = (float)h[0];
    fbuf[bs * 500 + tid * 10 + 2 * p + 1] = (float)h[1];
  }
}

// ---------------------------------------------------------------------------
// Per-(batch, direction) MHA + sum over queries + final dense + softmax.
// ---------------------------------------------------------------------------
__global__ __launch_bounds__(256) void mha_kernel(
    const float* __restrict__ fbuf,
    const float* __restrict__ wq, const float* __restrict__ bq,
    const float* __restrict__ wk, const float* __restrict__ bk,
    const float* __restrict__ wv, const float* __restrict__ bv,
    const float* __restrict__ wo, const float* __restrict__ bo,
    const float* __restrict__ wf, const float* __restrict__ bf,
    float* __restrict__ out) {
  __shared__ float f[2][50][10];
  __shared__ float Qm[50][2][10];
  __shared__ float Km[50][2][10];
  __shared__ float Vm[50][2][10];
  __shared__ float A2[2][50][50];
  __shared__ float Abar[2][50];
  __shared__ float OS[2][10];
  __shared__ float rr[10];

  int blk = blockIdx.x, b = blk >> 1, dir = blk & 1;
  int qs = dir, ks = dir ^ 1;
  int tid = threadIdx.x;

  for (int i = tid; i < 1000; i += 256) (&f[0][0][0])[i] = fbuf[b * 1000 + i];
  __syncthreads();

  for (int i = tid; i < 1000; i += 256) {
    int q = i / 20, rem = i - q * 20;
    int h = rem / 10, e = rem - h * 10;
    const float* fq = f[qs][q];
    const float* fk = f[ks][q];
    float aq = bq[h * 10 + e], ak = bk[h * 10 + e], av = bv[h * 10 + e];
#pragma unroll
    for (int dd = 0; dd < 10; ++dd) {
      int wIdx = dd * 20 + h * 10 + e;
      aq = fmaf(fq[dd], wq[wIdx], aq);
      ak = fmaf(fk[dd], wk[wIdx], ak);
      av = fmaf(fk[dd], wv[wIdx], av);
    }
    Qm[q][h][e] = aq; Km[q][h][e] = ak; Vm[q][h][e] = av;
  }
  __syncthreads();

  for (int row = tid; row < 100; row += 256) {
    int h = row / 50, q = row - h * 50;
    const float* Qr = Qm[q][h];
    float lg[50], m = -1e30f;
#pragma unroll
    for (int s = 0; s < 50; ++s) {
      const float* Kr = Km[s][h];
      float t = 0.0f;
#pragma unroll
      for (int e = 0; e < 10; ++e) t = fmaf(Qr[e], Kr[e], t);
      t *= 0.31622776601683794f;   // 1/sqrt(10)
      lg[s] = t; m = fmaxf(m, t);
    }
    float sum = 0.0f;
#pragma unroll
    for (int s = 0; s < 50; ++s) { float p = __expf(lg[s] - m); lg[s] = p; sum += p; }
    float inv = 1.0f / sum;
#pragma unroll
    for (int s = 0; s < 50; ++s) A2[h][q][s] = lg[s] * inv;
  }
  __syncthreads();

  for (int i = tid; i < 100; i += 256) {
    int h = i / 50, s = i - h * 50;
    float t = 0.0f;
#pragma unroll
    for (int q = 0; q < 50; ++q) t += A2[h][q][s];
    Abar[h][s] = t;
  }
  __syncthreads();
  if (tid < 20) {
    int h = tid / 10, e = tid - h * 10;
    float t = 0.0f;
#pragma unroll
    for (int s = 0; s < 50; ++s) t += Abar[h][s] * Vm[s][h][e];
    OS[h][e] = t;
  }
  __syncthreads();
  if (tid < 10) {
    int dc = tid;
    float t = 50.0f * bo[dc];
#pragma unroll
    for (int h = 0; h < 2; ++h)
#pragma unroll
      for (int e = 0; e < 10; ++e) t = fmaf(OS[h][e], wo[h * 100 + e * 10 + dc], t);
    rr[dc] = t;
  }
  __syncthreads();
  if (tid == 0) {
    float l0 = bf[0], l1 = bf[1];
#pragma unroll
    for (int dd = 0; dd < 10; ++dd) {
      l0 = fmaf(rr[dd], wf[dd * 2 + 0], l0);
      l1 = fmaf(rr[dd], wf[dd * 2 + 1], l1);
    }
    float m = fmaxf(l0, l1);
    float e0 = expf(l0 - m), e1 = expf(l1 - m);
    float inv = 1.0f / (e0 + e1);
    out[(b * 2 + dir) * 2 + 0] = e0 * inv;
    out[(b * 2 + dir) * 2 + 1] = e1 * inv;
  }
}

// ---------------------------------------------------------------------------
extern "C" void kernel_launch(void* const* d_in, const int* in_sizes, int n_in,
                              void* d_out, int out_size, void* d_ws, size_t ws_size,
                              hipStream_t stream) {
  const int*   inputs = (const int*)d_in[0];
  const float* emb = (const float*)d_in[1];
  const float* w1 = (const float*)d_in[2];
  const float* b1 = (const float*)d_in[3];
  const float* w2 = (const float*)d_in[4];
  const float* b2 = (const float*)d_in[5];
  const float* w3 = (const float*)d_in[6];
  const float* b3 = (const float*)d_in[7];
  const float* wq = (const float*)d_in[8];
  const float* bq = (const float*)d_in[9];
  const float* wk = (const float*)d_in[10];
  const float* bk = (const float*)d_in[11];
  const float* wv = (const float*)d_in[12];
  const float* bv = (const float*)d_in[13];
  const float* wo = (const float*)d_in[14];
  const float* bo = (const float*)d_in[15];
  const float* wf = (const float*)d_in[16];
  const float* bf = (const float*)d_in[17];
  float* out = (float*)d_out;

  float* fbuf = (float*)d_ws;                         // 32768 f32
  unsigned* candp = (unsigned*)((float*)d_ws + 32768);   // 64*5*37*50 u32
  unsigned short* bh = (unsigned short*)((float*)d_ws + 1216768);   // 3*9*64*8 u16
  unsigned short* emb16 = bh + 16384;                 // 8001*16 u16 (32B-aligned)

  hipLaunchKernelGGL(prep_kernel, dim3(39), dim3(256), 0, stream,
                     emb, w1, w2, w3, emb16, bh);
  hipLaunchKernelGGL(conv_fused_kernel, dim3(NBS * NCHK), dim3(512), 0, stream,
                     inputs, emb16, b1, b2, b3, bh, candp);
  hipLaunchKernelGGL(merge_topk_kernel, dim3(NBS * 5), dim3(256), 0, stream, candp, fbuf);
  hipLaunchKernelGGL(mha_kernel, dim3(NBS), dim3(256), 0, stream,
                     fbuf, wq, bq, wk, bk, wv, bv, wo, bo, wf, bf, out);
}

// Round 17
// 147.564 us; speedup vs baseline: 1.7391x; 1.7391x over previous
//
#include <hip/hip_runtime.h>
#include <hip/hip_bf16.h>

#define LSEQ   16384
#define BATCH  32
#define NBS    64              // B*2 sequences
#define NW     8000
#define CHUNK  448             // output rows per block
#define NCHK   37              // ceil(16384/448)
#define ROWS   536             // LDS plane rows: seq [base-32, base+504)
#define RS     24              // row stride in ushorts (48 B: 16 bf16 data + 8 pad)

typedef short v8s __attribute__((ext_vector_type(8)));   // 8 bf16 = 4 VGPR
typedef float v4f __attribute__((ext_vector_type(4)));   // MFMA acc
typedef _Float16 hf2 __attribute__((ext_vector_type(2)));  // packed f16 pair

__device__ __forceinline__ unsigned short f2bf(float f) {   // RTNE f32->bf16
  unsigned u = __float_as_uint(f);
  unsigned r = u + 0x7FFFu + ((u >> 16) & 1u);
  return (unsigned short)(r >> 16);
}
__device__ __forceinline__ unsigned short cvt_bf16(float v) {  // HW cvt
  __hip_bfloat16 hb = __float2bfloat16(v);
  unsigned short us;
  __builtin_memcpy(&us, &hb, 2);
  return us;
}

// ---------------------------------------------------------------------------
// Prep (r13-verified): blocks 0..31 build bf16 emb table [NW+1][16];
// blocks 32..40 build MFMA B-fragments (3*11*64 = 2112 entries -> NINE
// blocks; r15/r16 launched 7 and left stage-2 t>=6 fragments as 0xAA poison
// — that, not XCD coherence, was the 5.08e-2 failure).
// B[k=kh*16+wi][n] = W[kh][wi-n+10] (0 outside / n>=10); B-operand layout:
// lane l holds B[k=32t+8*((l>>4)&1)+j][col=l&15], kh=2t+(l>>5), j=0..7.
// ---------------------------------------------------------------------------
__global__ __launch_bounds__(256) void prep_kernel(
    const float* __restrict__ emb, const float* __restrict__ w1,
    const float* __restrict__ w2, const float* __restrict__ w3,
    unsigned short* __restrict__ emb16, unsigned short* __restrict__ bh) {
  int bid = blockIdx.x;
  if (bid < 32) {
    int r = bid * 256 + threadIdx.x;
    if (r > NW) return;
    const float2* er = reinterpret_cast<const float2*>(emb + r * 10);
    float v[10];
#pragma unroll
    for (int k = 0; k < 5; ++k) { float2 t2 = er[k]; v[2 * k] = t2.x; v[2 * k + 1] = t2.y; }
    v8s lo8 = (v8s)0, hi8 = (v8s)0;
#pragma unroll
    for (int j = 0; j < 8; ++j) lo8[j] = (short)f2bf(v[j]);
    hi8[0] = (short)f2bf(v[8]);
    hi8[1] = (short)f2bf(v[9]);
    v8s* dst = reinterpret_cast<v8s*>(emb16 + r * 16);
    dst[0] = lo8;
    dst[1] = hi8;
  } else {
    int idx = (bid - 32) * 256 + threadIdx.x;   // (stage*11 + t)*64 + lane
    if (idx >= 3 * 11 * 64) return;
    int lane = idx & 63, rest = idx >> 6;
    int t = rest % 11, stage = rest / 11;
    const float* W = (stage == 0) ? w1 : (stage == 1) ? w2 : w3;
    int col = lane & 15;
    int kh = 2 * t + (lane >> 5);
    int wi0 = ((lane >> 4) & 1) * 8;
#pragma unroll
    for (int j = 0; j < 8; ++j) {
      int wi = wi0 + j;
      int kw = wi - col + 10;
      float v = (wi < 10 && col < 10 && kw >= 0 && kw < 22) ? W[kh * 22 + kw] : 0.0f;
      bh[idx * 8 + j] = f2bf(v);
    }
  }
}

// ---------------------------------------------------------------------------
// Packed-pair (two channels per u32, f16x2) bitonic primitives (r12-verified).
// ---------------------------------------------------------------------------
__device__ __forceinline__ unsigned h2max_u(unsigned a, unsigned b) {
  hf2 r = __builtin_elementwise_max(__builtin_bit_cast(hf2, a),
                                    __builtin_bit_cast(hf2, b));
  return __builtin_bit_cast(unsigned, r);
}
__device__ __forceinline__ unsigned h2min_u(unsigned a, unsigned b) {
  hf2 r = __builtin_elementwise_min(__builtin_bit_cast(hf2, a),
                                    __builtin_bit_cast(hf2, b));
  return __builtin_bit_cast(unsigned, r);
}
__device__ __forceinline__ unsigned bsort64_h2(unsigned v, int lane) {
#pragma unroll
  for (int k = 2; k <= 64; k <<= 1) {
#pragma unroll
    for (int j = k >> 1; j > 0; j >>= 1) {
      unsigned o = __shfl_xor(v, j, 64);
      bool keepmax = (((lane & k) == 0) == ((lane & j) == 0));
      unsigned mx = h2max_u(v, o), mn = h2min_u(v, o);
      v = keepmax ? mx : mn;
    }
  }
  return v;
}
__device__ __forceinline__ unsigned bmerge64_h2(unsigned a, unsigned b, int lane) {
  unsigned rb = __shfl(b, 63 - lane, 64);
  unsigned m = h2max_u(a, rb);
#pragma unroll
  for (int j = 32; j > 0; j >>= 1) {
    unsigned o = __shfl_xor(m, j, 64);
    unsigned mx = h2max_u(m, o), mn = h2min_u(m, o);
    m = ((lane & j) == 0) ? mx : mn;
  }
  return m;
}

// ---------------------------------------------------------------------------
// Fused 3-layer conv via bf16 MFMA + packed-pair bitonic top-50
// (r13-verified, byte-identical).
// ---------------------------------------------------------------------------
__global__ __launch_bounds__(512, 6) void conv_fused_kernel(
    const int* __restrict__ inputs, const unsigned short* __restrict__ emb16,
    const float* __restrict__ b1, const float* __restrict__ b2,
    const float* __restrict__ b3,
    const unsigned short* __restrict__ bh,
    unsigned* __restrict__ candp /* [NBS*5][NCHK][50] packed */) {
  __shared__ unsigned short plane[ROWS * RS];   // 25.7 KB

  int blk = blockIdx.x;
  int bs = blk / NCHK;
  int chunk = blk - bs * NCHK;
  int base = chunk * CHUNK;
  int tid = threadIdx.x;
  int lane = tid & 63, wave = tid >> 6;

  // ---- gather: copy bf16 emb rows for seq [base-32, base+504) ----
  const int* tokp = inputs + bs * LSEQ;
  for (int i = tid; i < ROWS; i += 512) {
    int seq = base - 32 + i;
    v8s lo8 = (v8s)0, hi8 = (v8s)0;
    if ((unsigned)seq < (unsigned)LSEQ) {
      int tok = tokp[seq];
      const v8s* er = reinterpret_cast<const v8s*>(emb16 + tok * 16);
      lo8 = er[0];
      hi8 = er[1];
    }
    *reinterpret_cast<v8s*>(&plane[i * RS + 0]) = lo8;
    *reinterpret_cast<v8s*>(&plane[i * RS + 8]) = hi8;
  }
  __syncthreads();

  // lane-constant A address part: row (l&15)+(l>>5)+22 (incl +32 plane offset,
  // -10 kh shift), elem offset wi0 = ((l>>4)&1)*8.
  const int laneA = ((lane & 15) + (lane >> 5) + 22) * RS + ((lane >> 4) & 1) * 8;
  const int col = lane & 15;
  const int rbase = (lane >> 4) * 4;

#pragma unroll 1
  for (int stage = 0; stage < 3; ++stage) {
    const int lo = (stage == 0) ? -20 : (stage == 1) ? -10 : 0;
    const int ntiles = (stage == 0) ? 32 : (stage == 1) ? 30 : 28;
    const float bias = (stage == 0) ? b1[0] : (stage == 1) ? b2[0] : b3[0];
    const int nt = (ntiles - wave + 7) >> 3;     // tiles wave+8m, m<nt

    v4f acc[4];
#pragma unroll
    for (int m = 0; m < 4; ++m)
#pragma unroll
      for (int j = 0; j < 4; ++j) acc[m][j] = 0.0f;

    const v8s* bhf = reinterpret_cast<const v8s*>(bh) + (stage * 11) * 64 + lane;
    v8s bhc = bhf[0];

#pragma unroll 1
    for (int t = 0; t < 11; ++t) {
      v8s bhn = bhc;
      if (t < 10) bhn = bhf[(t + 1) * 64];
      const int toff = laneA + t * 2 * RS;
#pragma unroll
      for (int m = 0; m < 4; ++m) {
        if (m < nt) {
          int r0 = lo + (wave + 8 * m) * 16;
          v8s a = *reinterpret_cast<const v8s*>(&plane[toff + r0 * RS]);
          acc[m] = __builtin_amdgcn_mfma_f32_16x16x32_bf16(a, bhc, acc[m], 0, 0, 0);
        }
      }
      bhc = bhn;
    }
    __syncthreads();   // all reads complete before in-place writes

#pragma unroll
    for (int m = 0; m < 4; ++m) {
      if (m < nt) {
        int r0 = lo + (wave + 8 * m) * 16;
#pragma unroll
        for (int j = 0; j < 4; ++j) {
          int rloc = r0 + rbase + j;
          int seq = base + rloc;
          unsigned short us = cvt_bf16(fmaxf(acc[m][j] + bias, 0.0f));
          bool ok = (col < 10) && ((unsigned)seq < (unsigned)LSEQ);
          plane[(rloc + 32) * RS + col] = ok ? us : (unsigned short)0;
        }
      }
    }
    __syncthreads();
  }

  // ---- per-chunk exact top-50, one packed channel-pair stream per wave ----
  if (wave < 5) {
    int p = wave;                              // cols 2p, 2p+1
    unsigned x[7];
#pragma unroll
    for (int s = 0; s < 7; ++s) {
      unsigned w = *reinterpret_cast<const unsigned*>(
          &plane[(32 + s * 64 + lane) * RS + 2 * p]);
      float flo = __uint_as_float(w << 16);          // bf16 lo -> f32 (exact)
      float fhi = __uint_as_float(w & 0xFFFF0000u);  // bf16 hi -> f32 (exact)
      hf2 h;
      h[0] = (_Float16)flo;                          // f32 -> f16 (exact here)
      h[1] = (_Float16)fhi;
      x[s] = __builtin_bit_cast(unsigned, h);
    }
#pragma unroll
    for (int s = 0; s < 7; ++s) x[s] = bsort64_h2(x[s], lane);
    unsigned y0 = bmerge64_h2(x[0], x[1], lane);
    unsigned y1 = bmerge64_h2(x[2], x[3], lane);
    unsigned y2 = bmerge64_h2(x[4], x[5], lane);
    unsigned z0 = bmerge64_h2(y0, y1, lane);
    unsigned z1 = bmerge64_h2(y2, x[6], lane);
    unsigned t  = bmerge64_h2(z0, z1, lane);
    if (lane < 50)
      candp[((bs * 5 + p) * NCHK + chunk) * 50 + lane] = t;
  }
}

// ---------------------------------------------------------------------------
// MHA with fused candidate merge. Kernel boundary guarantees candp coherence.
// Each block (b, dir): waves tournament-merge the 10 packed streams of batch
// b's two sequences (37 sorted 50-lists -> 36 bmerge64, register-only, exact:
// invariant acc = top-64 of union so far) straight into the f[2][50][10] LDS
// tile, then run the r13 MHA body.
// ---------------------------------------------------------------------------
__global__ __launch_bounds__(256) void mha_kernel(
    const unsigned* __restrict__ candp,
    const float* __restrict__ wq, const float* __restrict__ bq,
    const float* __restrict__ wk, const float* __restrict__ bk,
    const float* __restrict__ wv, const float* __restrict__ bv,
    const float* __restrict__ wo, const float* __restrict__ bo,
    const float* __restrict__ wf, const float* __restrict__ bf,
    float* __restrict__ out) {
  __shared__ float f[2][50][10];
  __shared__ float Qm[50][2][10];
  __shared__ float Km[50][2][10];
  __shared__ float Vm[50][2][10];
  __shared__ float A2[2][50][50];
  __shared__ float Abar[2][50];
  __shared__ float OS[2][10];
  __shared__ float rr[10];

  int blk = blockIdx.x, b = blk >> 1, dir = blk & 1;
  int qs = dir, ks = dir ^ 1;
  int tid = threadIdx.x;
  int lane = tid & 63, wave = tid >> 6;

  // ---- merge: stream s = s2*5 + p (sequence bs = 2b + s2, channels 2p,2p+1)
  for (int s = wave; s < 10; s += 4) {
    int s2 = s / 5, p = s - s2 * 5;
    int bs = 2 * b + s2;
    const unsigned* src = candp + ((bs * 5 + p) * NCHK) * 50;
    unsigned acc = (lane < 50) ? src[lane] : 0u;
#pragma unroll 1
    for (int c = 1; c < NCHK; ++c) {
      unsigned cur = (lane < 50) ? src[c * 50 + lane] : 0u;
      acc = bmerge64_h2(acc, cur, lane);   // exact top-64 of union (desc)
    }
    if (lane < 50) {
      hf2 h = __builtin_bit_cast(hf2, acc);
      f[s2][lane][2 * p + 0] = (float)h[0];
      f[s2][lane][2 * p + 1] = (float)h[1];
    }
  }
  __syncthreads();

  for (int i = tid; i < 1000; i += 256) {
    int q = i / 20, rem = i - q * 20;
    int h = rem / 10, e = rem - h * 10;
    const float* fq = f[qs][q];
    const float* fk = f[ks][q];
    float aq = bq[h * 10 + e], ak = bk[h * 10 + e], av = bv[h * 10 + e];
#pragma unroll
    for (int dd = 0; dd < 10; ++dd) {
      int wIdx = dd * 20 + h * 10 + e;
      aq = fmaf(fq[dd], wq[wIdx], aq);
      ak = fmaf(fk[dd], wk[wIdx], ak);
      av = fmaf(fk[dd], wv[wIdx], av);
    }
    Qm[q][h][e] = aq; Km[q][h][e] = ak; Vm[q][h][e] = av;
  }
  __syncthreads();

  for (int row = tid; row < 100; row += 256) {
    int h = row / 50, q = row - h * 50;
    const float* Qr = Qm[q][h];
    float lg[50], m = -1e30f;
#pragma unroll
    for (int s = 0; s < 50; ++s) {
      const float* Kr = Km[s][h];
      float t = 0.0f;
#pragma unroll
      for (int e = 0; e < 10; ++e) t = fmaf(Qr[e], Kr[e], t);
      t *= 0.31622776601683794f;   // 1/sqrt(10)
      lg[s] = t; m = fmaxf(m, t);
    }
    float sum = 0.0f;
#pragma unroll
    for (int s = 0; s < 50; ++s) { float p = __expf(lg[s] - m); lg[s] = p; sum += p; }
    float inv = 1.0f / sum;
#pragma unroll
    for (int s = 0; s < 50; ++s) A2[h][q][s] = lg[s] * inv;
  }
  __syncthreads();

  for (int i = tid; i < 100; i += 256) {
    int h = i / 50, s = i - h * 50;
    float t = 0.0f;
#pragma unroll
    for (int q = 0; q < 50; ++q) t += A2[h][q][s];
    Abar[h][s] = t;
  }
  __syncthreads();
  if (tid < 20) {
    int h = tid / 10, e = tid - h * 10;
    float t = 0.0f;
#pragma unroll
    for (int s = 0; s < 50; ++s) t += Abar[h][s] * Vm[s][h][e];
    OS[h][e] = t;
  }
  __syncthreads();
  if (tid < 10) {
    int dc = tid;
    float t = 50.0f * bo[dc];
#pragma unroll
    for (int h = 0; h < 2; ++h)
#pragma unroll
      for (int e = 0; e < 10; ++e) t = fmaf(OS[h][e], wo[h * 100 + e * 10 + dc], t);
    rr[dc] = t;
  }
  __syncthreads();
  if (tid == 0) {
    float l0 = bf[0], l1 = bf[1];
#pragma unroll
    for (int dd = 0; dd < 10; ++dd) {
      l0 = fmaf(rr[dd], wf[dd * 2 + 0], l0);
      l1 = fmaf(rr[dd], wf[dd * 2 + 1], l1);
    }
    float m = fmaxf(l0, l1);
    float e0 = expf(l0 - m), e1 = expf(l1 - m);
    float inv = 1.0f / (e0 + e1);
    out[(b * 2 + dir) * 2 + 0] = e0 * inv;
    out[(b * 2 + dir) * 2 + 1] = e1 * inv;
  }
}

// ---------------------------------------------------------------------------
extern "C" void kernel_launch(void* const* d_in, const int* in_sizes, int n_in,
                              void* d_out, int out_size, void* d_ws, size_t ws_size,
                              hipStream_t stream) {
  const int*   inputs = (const int*)d_in[0];
  const float* emb = (const float*)d_in[1];
  const float* w1 = (const float*)d_in[2];
  const float* b1 = (const float*)d_in[3];
  const float* w2 = (const float*)d_in[4];
  const float* b2 = (const float*)d_in[5];
  const float* w3 = (const float*)d_in[6];
  const float* b3 = (const float*)d_in[7];
  const float* wq = (const float*)d_in[8];
  const float* bq = (const float*)d_in[9];
  const float* wk = (const float*)d_in[10];
  const float* bk = (const float*)d_in[11];
  const float* wv = (const float*)d_in[12];
  const float* bv = (const float*)d_in[13];
  const float* wo = (const float*)d_in[14];
  const float* bo = (const float*)d_in[15];
  const float* wf = (const float*)d_in[16];
  const float* bf = (const float*)d_in[17];
  float* out = (float*)d_out;

  unsigned* candp = (unsigned*)((float*)d_ws + 32768);   // 64*5*37*50 u32
  unsigned short* bh = (unsigned short*)((float*)d_ws + 1216768);   // 16896 u16
  unsigned short* emb16 = bh + 16896;                 // 8001*16 u16 (16B-aligned)

  // 41 blocks: 32 emb + 9 bfrag (2112 entries). r15/r16 launched 7 bfrag
  // blocks -> stage-2 t>=6 fragments stayed 0xAA-poisoned -> absmax 5e-2.
  hipLaunchKernelGGL(prep_kernel, dim3(41), dim3(256), 0, stream,
                     emb, w1, w2, w3, emb16, bh);
  hipLaunchKernelGGL(conv_fused_kernel, dim3(NBS * NCHK), dim3(512), 0, stream,
                     inputs, emb16, b1, b2, b3, bh, candp);
  hipLaunchKernelGGL(mha_kernel, dim3(NBS), dim3(256), 0, stream,
                     candp, wq, bq, wk, bk, wv, bv, wo, bo, wf, bf, out);
}

// Round 18
// 115.299 us; speedup vs baseline: 2.2257x; 1.2798x over previous
//
#include <hip/hip_runtime.h>
#include <hip/hip_bf16.h>

#define LSEQ   16384
#define BATCH  32
#define NBS    64              // B*2 sequences
#define NW     8000
#define CHUNK  448             // output rows per block
#define NCHK   37              // ceil(16384/448)
#define ROWS   536             // LDS plane rows: seq [base-32, base+504)
#define RS     24              // row stride in ushorts (48 B: 16 bf16 data + 8 pad)

typedef short v8s __attribute__((ext_vector_type(8)));   // 8 bf16 = 4 VGPR
typedef float v4f __attribute__((ext_vector_type(4)));   // MFMA acc
typedef _Float16 hf2 __attribute__((ext_vector_type(2)));  // packed f16 pair

__device__ __forceinline__ unsigned short f2bf(float f) {   // RTNE f32->bf16
  unsigned u = __float_as_uint(f);
  unsigned r = u + 0x7FFFu + ((u >> 16) & 1u);
  return (unsigned short)(r >> 16);
}
__device__ __forceinline__ unsigned short cvt_bf16(float v) {  // HW cvt
  __hip_bfloat16 hb = __float2bfloat16(v);
  unsigned short us;
  __builtin_memcpy(&us, &hb, 2);
  return us;
}

// ---------------------------------------------------------------------------
// Prep (r13/r17-verified): blocks 0..31 build bf16 emb table [NW+1][16];
// blocks 32..40 build MFMA B-fragments (3*11*64 = 2112 entries -> 9 blocks).
// B[k=kh*16+wi][n] = W[kh][wi-n+10] (0 outside / n>=10); B-operand layout:
// lane l holds B[k=32t+8*((l>>4)&1)+j][col=l&15], kh=2t+(l>>5), j=0..7.
// ---------------------------------------------------------------------------
__global__ __launch_bounds__(256) void prep_kernel(
    const float* __restrict__ emb, const float* __restrict__ w1,
    const float* __restrict__ w2, const float* __restrict__ w3,
    unsigned short* __restrict__ emb16, unsigned short* __restrict__ bh) {
  int bid = blockIdx.x;
  if (bid < 32) {
    int r = bid * 256 + threadIdx.x;
    if (r > NW) return;
    const float2* er = reinterpret_cast<const float2*>(emb + r * 10);
    float v[10];
#pragma unroll
    for (int k = 0; k < 5; ++k) { float2 t2 = er[k]; v[2 * k] = t2.x; v[2 * k + 1] = t2.y; }
    v8s lo8 = (v8s)0, hi8 = (v8s)0;
#pragma unroll
    for (int j = 0; j < 8; ++j) lo8[j] = (short)f2bf(v[j]);
    hi8[0] = (short)f2bf(v[8]);
    hi8[1] = (short)f2bf(v[9]);
    v8s* dst = reinterpret_cast<v8s*>(emb16 + r * 16);
    dst[0] = lo8;
    dst[1] = hi8;
  } else {
    int idx = (bid - 32) * 256 + threadIdx.x;   // (stage*11 + t)*64 + lane
    if (idx >= 3 * 11 * 64) return;
    int lane = idx & 63, rest = idx >> 6;
    int t = rest % 11, stage = rest / 11;
    const float* W = (stage == 0) ? w1 : (stage == 1) ? w2 : w3;
    int col = lane & 15;
    int kh = 2 * t + (lane >> 5);
    int wi0 = ((lane >> 4) & 1) * 8;
#pragma unroll
    for (int j = 0; j < 8; ++j) {
      int wi = wi0 + j;
      int kw = wi - col + 10;
      float v = (wi < 10 && col < 10 && kw >= 0 && kw < 22) ? W[kh * 22 + kw] : 0.0f;
      bh[idx * 8 + j] = f2bf(v);
    }
  }
}

// ---------------------------------------------------------------------------
// Packed-pair (two channels per u32, f16x2) bitonic primitives (r12-verified).
// ---------------------------------------------------------------------------
__device__ __forceinline__ unsigned h2max_u(unsigned a, unsigned b) {
  hf2 r = __builtin_elementwise_max(__builtin_bit_cast(hf2, a),
                                    __builtin_bit_cast(hf2, b));
  return __builtin_bit_cast(unsigned, r);
}
__device__ __forceinline__ unsigned h2min_u(unsigned a, unsigned b) {
  hf2 r = __builtin_elementwise_min(__builtin_bit_cast(hf2, a),
                                    __builtin_bit_cast(hf2, b));
  return __builtin_bit_cast(unsigned, r);
}
__device__ __forceinline__ unsigned bsort64_h2(unsigned v, int lane) {
#pragma unroll
  for (int k = 2; k <= 64; k <<= 1) {
#pragma unroll
    for (int j = k >> 1; j > 0; j >>= 1) {
      unsigned o = __shfl_xor(v, j, 64);
      bool keepmax = (((lane & k) == 0) == ((lane & j) == 0));
      unsigned mx = h2max_u(v, o), mn = h2min_u(v, o);
      v = keepmax ? mx : mn;
    }
  }
  return v;
}
__device__ __forceinline__ unsigned bmerge64_h2(unsigned a, unsigned b, int lane) {
  unsigned rb = __shfl(b, 63 - lane, 64);
  unsigned m = h2max_u(a, rb);
#pragma unroll
  for (int j = 32; j > 0; j >>= 1) {
    unsigned o = __shfl_xor(m, j, 64);
    unsigned mx = h2max_u(m, o), mn = h2min_u(m, o);
    m = ((lane & j) == 0) ? mx : mn;
  }
  return m;
}

// ---------------------------------------------------------------------------
// Fused 3-layer conv via bf16 MFMA + packed-pair bitonic top-50
// (r13/r17-verified, byte-identical).
// ---------------------------------------------------------------------------
__global__ __launch_bounds__(512, 6) void conv_fused_kernel(
    const int* __restrict__ inputs, const unsigned short* __restrict__ emb16,
    const float* __restrict__ b1, const float* __restrict__ b2,
    const float* __restrict__ b3,
    const unsigned short* __restrict__ bh,
    unsigned* __restrict__ candp /* [NBS*5][NCHK][50] packed */) {
  __shared__ unsigned short plane[ROWS * RS];   // 25.7 KB

  int blk = blockIdx.x;
  int bs = blk / NCHK;
  int chunk = blk - bs * NCHK;
  int base = chunk * CHUNK;
  int tid = threadIdx.x;
  int lane = tid & 63, wave = tid >> 6;

  // ---- gather: copy bf16 emb rows for seq [base-32, base+504) ----
  const int* tokp = inputs + bs * LSEQ;
  for (int i = tid; i < ROWS; i += 512) {
    int seq = base - 32 + i;
    v8s lo8 = (v8s)0, hi8 = (v8s)0;
    if ((unsigned)seq < (unsigned)LSEQ) {
      int tok = tokp[seq];
      const v8s* er = reinterpret_cast<const v8s*>(emb16 + tok * 16);
      lo8 = er[0];
      hi8 = er[1];
    }
    *reinterpret_cast<v8s*>(&plane[i * RS + 0]) = lo8;
    *reinterpret_cast<v8s*>(&plane[i * RS + 8]) = hi8;
  }
  __syncthreads();

  // lane-constant A address part: row (l&15)+(l>>5)+22 (incl +32 plane offset,
  // -10 kh shift), elem offset wi0 = ((l>>4)&1)*8.
  const int laneA = ((lane & 15) + (lane >> 5) + 22) * RS + ((lane >> 4) & 1) * 8;
  const int col = lane & 15;
  const int rbase = (lane >> 4) * 4;

#pragma unroll 1
  for (int stage = 0; stage < 3; ++stage) {
    const int lo = (stage == 0) ? -20 : (stage == 1) ? -10 : 0;
    const int ntiles = (stage == 0) ? 32 : (stage == 1) ? 30 : 28;
    const float bias = (stage == 0) ? b1[0] : (stage == 1) ? b2[0] : b3[0];
    const int nt = (ntiles - wave + 7) >> 3;     // tiles wave+8m, m<nt

    v4f acc[4];
#pragma unroll
    for (int m = 0; m < 4; ++m)
#pragma unroll
      for (int j = 0; j < 4; ++j) acc[m][j] = 0.0f;

    const v8s* bhf = reinterpret_cast<const v8s*>(bh) + (stage * 11) * 64 + lane;
    v8s bhc = bhf[0];

#pragma unroll 1
    for (int t = 0; t < 11; ++t) {
      v8s bhn = bhc;
      if (t < 10) bhn = bhf[(t + 1) * 64];
      const int toff = laneA + t * 2 * RS;
#pragma unroll
      for (int m = 0; m < 4; ++m) {
        if (m < nt) {
          int r0 = lo + (wave + 8 * m) * 16;
          v8s a = *reinterpret_cast<const v8s*>(&plane[toff + r0 * RS]);
          acc[m] = __builtin_amdgcn_mfma_f32_16x16x32_bf16(a, bhc, acc[m], 0, 0, 0);
        }
      }
      bhc = bhn;
    }
    __syncthreads();   // all reads complete before in-place writes

#pragma unroll
    for (int m = 0; m < 4; ++m) {
      if (m < nt) {
        int r0 = lo + (wave + 8 * m) * 16;
#pragma unroll
        for (int j = 0; j < 4; ++j) {
          int rloc = r0 + rbase + j;
          int seq = base + rloc;
          unsigned short us = cvt_bf16(fmaxf(acc[m][j] + bias, 0.0f));
          bool ok = (col < 10) && ((unsigned)seq < (unsigned)LSEQ);
          plane[(rloc + 32) * RS + col] = ok ? us : (unsigned short)0;
        }
      }
    }
    __syncthreads();
  }

  // ---- per-chunk exact top-50, one packed channel-pair stream per wave ----
  if (wave < 5) {
    int p = wave;                              // cols 2p, 2p+1
    unsigned x[7];
#pragma unroll
    for (int s = 0; s < 7; ++s) {
      unsigned w = *reinterpret_cast<const unsigned*>(
          &plane[(32 + s * 64 + lane) * RS + 2 * p]);
      float flo = __uint_as_float(w << 16);          // bf16 lo -> f32 (exact)
      float fhi = __uint_as_float(w & 0xFFFF0000u);  // bf16 hi -> f32 (exact)
      hf2 h;
      h[0] = (_Float16)flo;                          // f32 -> f16 (exact here)
      h[1] = (_Float16)fhi;
      x[s] = __builtin_bit_cast(unsigned, h);
    }
#pragma unroll
    for (int s = 0; s < 7; ++s) x[s] = bsort64_h2(x[s], lane);
    unsigned y0 = bmerge64_h2(x[0], x[1], lane);
    unsigned y1 = bmerge64_h2(x[2], x[3], lane);
    unsigned y2 = bmerge64_h2(x[4], x[5], lane);
    unsigned z0 = bmerge64_h2(y0, y1, lane);
    unsigned z1 = bmerge64_h2(y2, x[6], lane);
    unsigned t  = bmerge64_h2(z0, z1, lane);
    if (lane < 50)
      candp[((bs * 5 + p) * NCHK + chunk) * 50 + lane] = t;
  }
}

// ---------------------------------------------------------------------------
// MHA with fused candidate merge (r17 structure, LATENCY-FIXED).
// r17's merge was a 36-deep serially-dependent load+merge chain (~25us of
// unhidden L2 latency at 64 blocks). Fix: load all 37 chunk values into
// registers as INDEPENDENT loads (one vmcnt drain), then run the 36-step
// bitonic-merge chain as pure VALU. Exact (invariant: acc = top-64 of union).
// ---------------------------------------------------------------------------
__global__ __launch_bounds__(256) void mha_kernel(
    const unsigned* __restrict__ candp,
    const float* __restrict__ wq, const float* __restrict__ bq,
    const float* __restrict__ wk, const float* __restrict__ bk,
    const float* __restrict__ wv, const float* __restrict__ bv,
    const float* __restrict__ wo, const float* __restrict__ bo,
    const float* __restrict__ wf, const float* __restrict__ bf,
    float* __restrict__ out) {
  __shared__ float f[2][50][10];
  __shared__ float Qm[50][2][10];
  __shared__ float Km[50][2][10];
  __shared__ float Vm[50][2][10];
  __shared__ float A2[2][50][50];
  __shared__ float Abar[2][50];
  __shared__ float OS[2][10];
  __shared__ float rr[10];

  int blk = blockIdx.x, b = blk >> 1, dir = blk & 1;
  int qs = dir, ks = dir ^ 1;
  int tid = threadIdx.x;
  int lane = tid & 63, wave = tid >> 6;

  // ---- merge: stream s = s2*5 + p (sequence bs = 2b + s2, channels 2p,2p+1)
  for (int s = wave; s < 10; s += 4) {
    int s2 = s / 5, p = s - s2 * 5;
    int bs = 2 * b + s2;
    const unsigned* src = candp + ((bs * 5 + p) * NCHK) * 50;
    unsigned v[NCHK];
    if (lane < 50) {
#pragma unroll
      for (int c = 0; c < NCHK; ++c) v[c] = src[c * 50 + lane];   // independent
    } else {
#pragma unroll
      for (int c = 0; c < NCHK; ++c) v[c] = 0u;
    }
    unsigned acc = v[0];
#pragma unroll
    for (int c = 1; c < NCHK; ++c)
      acc = bmerge64_h2(acc, v[c], lane);      // pure-VALU chain
    if (lane < 50) {
      hf2 h = __builtin_bit_cast(hf2, acc);
      f[s2][lane][2 * p + 0] = (float)h[0];
      f[s2][lane][2 * p + 1] = (float)h[1];
    }
  }
  __syncthreads();

  for (int i = tid; i < 1000; i += 256) {
    int q = i / 20, rem = i - q * 20;
    int h = rem / 10, e = rem - h * 10;
    const float* fq = f[qs][q];
    const float* fk = f[ks][q];
    float aq = bq[h * 10 + e], ak = bk[h * 10 + e], av = bv[h * 10 + e];
#pragma unroll
    for (int dd = 0; dd < 10; ++dd) {
      int wIdx = dd * 20 + h * 10 + e;
      aq = fmaf(fq[dd], wq[wIdx], aq);
      ak = fmaf(fk[dd], wk[wIdx], ak);
      av = fmaf(fk[dd], wv[wIdx], av);
    }
    Qm[q][h][e] = aq; Km[q][h][e] = ak; Vm[q][h][e] = av;
  }
  __syncthreads();

  for (int row = tid; row < 100; row += 256) {
    int h = row / 50, q = row - h * 50;
    const float* Qr = Qm[q][h];
    float lg[50], m = -1e30f;
#pragma unroll
    for (int s = 0; s < 50; ++s) {
      const float* Kr = Km[s][h];
      float t = 0.0f;
#pragma unroll
      for (int e = 0; e < 10; ++e) t = fmaf(Qr[e], Kr[e], t);
      t *= 0.31622776601683794f;   // 1/sqrt(10)
      lg[s] = t; m = fmaxf(m, t);
    }
    float sum = 0.0f;
#pragma unroll
    for (int s = 0; s < 50; ++s) { float p = __expf(lg[s] - m); lg[s] = p; sum += p; }
    float inv = 1.0f / sum;
#pragma unroll
    for (int s = 0; s < 50; ++s) A2[h][q][s] = lg[s] * inv;
  }
  __syncthreads();

  for (int i = tid; i < 100; i += 256) {
    int h = i / 50, s = i - h * 50;
    float t = 0.0f;
#pragma unroll
    for (int q = 0; q < 50; ++q) t += A2[h][q][s];
    Abar[h][s] = t;
  }
  __syncthreads();
  if (tid < 20) {
    int h = tid / 10, e = tid - h * 10;
    float t = 0.0f;
#pragma unroll
    for (int s = 0; s < 50; ++s) t += Abar[h][s] * Vm[s][h][e];
    OS[h][e] = t;
  }
  __syncthreads();
  if (tid < 10) {
    int dc = tid;
    float t = 50.0f * bo[dc];
#pragma unroll
    for (int h = 0; h < 2; ++h)
#pragma unroll
      for (int e = 0; e < 10; ++e) t = fmaf(OS[h][e], wo[h * 100 + e * 10 + dc], t);
    rr[dc] = t;
  }
  __syncthreads();
  if (tid == 0) {
    float l0 = bf[0], l1 = bf[1];
#pragma unroll
    for (int dd = 0; dd < 10; ++dd) {
      l0 = fmaf(rr[dd], wf[dd * 2 + 0], l0);
      l1 = fmaf(rr[dd], wf[dd * 2 + 1], l1);
    }
    float m = fmaxf(l0, l1);
    float e0 = expf(l0 - m), e1 = expf(l1 - m);
    float inv = 1.0f / (e0 + e1);
    out[(b * 2 + dir) * 2 + 0] = e0 * inv;
    out[(b * 2 + dir) * 2 + 1] = e1 * inv;
  }
}

// ---------------------------------------------------------------------------
extern "C" void kernel_launch(void* const* d_in, const int* in_sizes, int n_in,
                              void* d_out, int out_size, void* d_ws, size_t ws_size,
                              hipStream_t stream) {
  const int*   inputs = (const int*)d_in[0];
  const float* emb = (const float*)d_in[1];
  const float* w1 = (const float*)d_in[2];
  const float* b1 = (const float*)d_in[3];
  const float* w2 = (const float*)d_in[4];
  const float* b2 = (const float*)d_in[5];
  const float* w3 = (const float*)d_in[6];
  const float* b3 = (const float*)d_in[7];
  const float* wq = (const float*)d_in[8];
  const float* bq = (const float*)d_in[9];
  const float* wk = (const float*)d_in[10];
  const float* bk = (const float*)d_in[11];
  const float* wv = (const float*)d_in[12];
  const float* bv = (const float*)d_in[13];
  const float* wo = (const float*)d_in[14];
  const float* bo = (const float*)d_in[15];
  const float* wf = (const float*)d_in[16];
  const float* bf = (const float*)d_in[17];
  float* out = (float*)d_out;

  unsigned* candp = (unsigned*)((float*)d_ws + 32768);   // 64*5*37*50 u32
  unsigned short* bh = (unsigned short*)((float*)d_ws + 1216768);   // 16896 u16
  unsigned short* emb16 = bh + 16896;                 // 8001*16 u16 (16B-aligned)

  // 41 blocks: 32 emb + 9 bfrag (2112 entries).
  hipLaunchKernelGGL(prep_kernel, dim3(41), dim3(256), 0, stream,
                     emb, w1, w2, w3, emb16, bh);
  hipLaunchKernelGGL(conv_fused_kernel, dim3(NBS * NCHK), dim3(512), 0, stream,
                     inputs, emb16, b1, b2, b3, bh, candp);
  hipLaunchKernelGGL(mha_kernel, dim3(NBS), dim3(256), 0, stream,
                     candp, wq, bq, wk, bk, wv, bv, wo, bo, wf, bf, out);
}